// Round 1
// baseline (154.347 us; speedup 1.0000x reference)
//
#include <hip/hip_runtime.h>
#include <hip/hip_bf16.h>

// Problem: B=64, K=8, H=W=128 (HW=16384). float32 in/out.
// out[0] = loss scalar; out[1..] = pred_perm (B,K,H,W) flat.

#define BB 64
#define KK 8
#define HW 16384
#define EPSF 1e-15f

// ---------- compile-time mask table: all 255 nonzero 8-bit masks, level-ordered by popcount ----------
struct MaskTab {
    unsigned char masks[255];
    int off[9];   // off[p-1] = start of popcount-p level; off[8] = 255
};

constexpr MaskTab make_tab() {
    MaskTab t{};
    int idx = 0;
    for (int p = 1; p <= 8; ++p) {
        t.off[p - 1] = idx;
        for (int m = 1; m < 256; ++m) {
            int c = 0;
            for (int b = 0; b < 8; ++b) c += (m >> b) & 1;
            if (c == p) t.masks[idx++] = (unsigned char)m;
        }
    }
    t.off[8] = idx; // 255
    return t;
}

__constant__ MaskTab kTab = make_tab();

// ---------- phase 1: ent[b][j] and cross[b][i][j] (raw sums over HW) ----------
// grid: B*8 blocks of 256 threads; block handles 2048 hw positions (2 float4 iters/thread).
__global__ __launch_bounds__(256) void cost_kernel(const float* __restrict__ pred,
                                                   const float* __restrict__ aug,
                                                   float* __restrict__ ws_cross,  // [B][8][8] (i,j)
                                                   float* __restrict__ ws_ent)    // [B][8]
{
    const int b     = blockIdx.x >> 3;
    const int chunk = blockIdx.x & 7;
    const int tid   = threadIdx.x;

    const float* p_base = pred + (size_t)b * (KK * HW);
    const float* t_base = aug  + (size_t)b * (KK * HW);

    float acc[64];
    float ent[8];
#pragma unroll
    for (int v = 0; v < 64; ++v) acc[v] = 0.f;
#pragma unroll
    for (int j = 0; j < 8; ++j) ent[j] = 0.f;

    for (int it = 0; it < 2; ++it) {
        const int hw = chunk * 2048 + it * 1024 + tid * 4;

        float4 lp[8];
#pragma unroll
        for (int i = 0; i < 8; ++i) {
            float4 p4 = *(const float4*)(p_base + i * HW + hw);
            lp[i].x = __logf(p4.x + EPSF);
            lp[i].y = __logf(p4.y + EPSF);
            lp[i].z = __logf(p4.z + EPSF);
            lp[i].w = __logf(p4.w + EPSF);
        }
#pragma unroll
        for (int j = 0; j < 8; ++j) {
            float4 t4 = *(const float4*)(t_base + j * HW + hw);
            float4 lt;
            lt.x = __logf(t4.x + EPSF);
            lt.y = __logf(t4.y + EPSF);
            lt.z = __logf(t4.z + EPSF);
            lt.w = __logf(t4.w + EPSF);
            ent[j] += t4.x * lt.x + t4.y * lt.y + t4.z * lt.z + t4.w * lt.w;
#pragma unroll
            for (int i = 0; i < 8; ++i) {
                acc[i * 8 + j] += t4.x * lp[i].x + t4.y * lp[i].y +
                                  t4.z * lp[i].z + t4.w * lp[i].w;
            }
        }
    }

    // wave-wide butterfly allreduce (64 lanes)
#pragma unroll
    for (int v = 0; v < 64; ++v) {
        float s = acc[v];
#pragma unroll
        for (int d = 1; d < 64; d <<= 1) s += __shfl_xor(s, d);
        acc[v] = s;
    }
#pragma unroll
    for (int j = 0; j < 8; ++j) {
        float s = ent[j];
#pragma unroll
        for (int d = 1; d < 64; d <<= 1) s += __shfl_xor(s, d);
        ent[j] = s;
    }

    if ((tid & 63) == 0) {
#pragma unroll
        for (int v = 0; v < 64; ++v) atomicAdd(&ws_cross[b * 64 + v], acc[v]);
#pragma unroll
        for (int j = 0; j < 8; ++j) atomicAdd(&ws_ent[b * 8 + j], ent[j]);
    }
}

// ---------- phase 2: Held-Karp assignment DP per batch; writes inv perm + loss ----------
// grid: B blocks of 64 threads (1 wave). Lanes: group = lane>>3 handles one mask,
// j = lane&7 is the candidate column; 3-step shfl_xor min-reduce within group.
__global__ __launch_bounds__(64) void assign_kernel(const float* __restrict__ ws_cross,
                                                    const float* __restrict__ ws_ent,
                                                    int* __restrict__ ws_inv,     // [B][8]: col -> src row
                                                    float* __restrict__ loss_out)
{
    __shared__ float C[64];     // C[i*8+j] = ent[j] - cross[i][j]  (unscaled)
    __shared__ float dp[256];
    __shared__ int   choice[256];

    const int b    = blockIdx.x;
    const int lane = threadIdx.x;
    const int grp  = lane >> 3;
    const int j    = lane & 7;

    C[lane] = ws_ent[b * 8 + j] - ws_cross[b * 64 + lane];
    if (lane == 0) dp[0] = 0.f;
    __syncthreads();

    for (int p = 1; p <= 8; ++p) {
        const int start = kTab.off[p - 1];
        const int end   = kTab.off[p];
        const float* Crow = &C[(p - 1) * 8];
        for (int base = start; base < end; base += 8) {
            const int mi = base + grp;
            if (mi < end) {
                const int M = kTab.masks[mi];
                float v  = 1e30f;
                int   bj = 0;
                if (M & (1 << j)) {
                    v  = dp[M ^ (1 << j)] + Crow[j];
                    bj = j;
                }
#pragma unroll
                for (int d = 1; d < 8; d <<= 1) {
                    float ov = __shfl_xor(v, d);
                    int   oj = __shfl_xor(bj, d);
                    if (ov < v) { v = ov; bj = oj; }
                }
                if (j == 0) { dp[M] = v; choice[M] = bj; }
            }
        }
        __syncthreads();
    }

    if (lane == 0) {
        int mask = 255;
        for (int r = 7; r >= 0; --r) {
            const int jj = choice[mask];
            ws_inv[b * 8 + jj] = r;       // column jj takes pred row r
            mask ^= 1 << jj;
        }
        // loss contribution: dp_min / (HW * B * K)
        atomicAdd(loss_out, dp[255] * (1.0f / (16384.0f * 512.0f)));
    }
}

// ---------- phase 3: permuted copy, out[1 + (b*8+j)*HW + e] = pred[(b*8+inv[b][j])*HW + e] ----------
// d_out+1 is only 4B-aligned -> scalar dword loads/stores, fully coalesced
// (lane t handles t + m*256 within the block's 2048-element chunk).
__global__ __launch_bounds__(256) void permute_kernel(const float* __restrict__ pred,
                                                      const int* __restrict__ ws_inv,
                                                      float* __restrict__ out)
{
    const int blk    = blockIdx.x;
    const int pair   = blk >> 3;      // b*8 + j  (0..511)
    const int cchunk = blk & 7;       // 8 chunks of 2048 per pair
    const int b      = pair >> 3;

    const int src_row = ws_inv[pair]; // uniform per block

    const float* src = pred + ((size_t)b * 8 + src_row) * HW + cchunk * 2048;
    float*       dst = out + 1 + (size_t)pair * HW + cchunk * 2048;

    const int t = threadIdx.x;
#pragma unroll
    for (int m = 0; m < 8; ++m) dst[t + m * 256] = src[t + m * 256];
}

extern "C" void kernel_launch(void* const* d_in, const int* in_sizes, int n_in,
                              void* d_out, int out_size, void* d_ws, size_t ws_size,
                              hipStream_t stream) {
    const float* pred = (const float*)d_in[0];
    const float* aug  = (const float*)d_in[1];
    float* out = (float*)d_out;

    float* ws_cross = (float*)d_ws;              // 64*64 floats
    float* ws_ent   = ws_cross + 64 * 64;        // 64*8 floats
    int*   ws_inv   = (int*)(ws_ent + 64 * 8);   // 64*8 ints

    // zero accumulation targets (ws is poisoned 0xAA before every timed launch)
    hipMemsetAsync(d_ws, 0, (size_t)(64 * 64 + 64 * 8) * sizeof(float), stream);
    hipMemsetAsync(d_out, 0, sizeof(float), stream);

    cost_kernel<<<dim3(BB * 8), dim3(256), 0, stream>>>(pred, aug, ws_cross, ws_ent);
    assign_kernel<<<dim3(BB), dim3(64), 0, stream>>>(ws_cross, ws_ent, ws_inv, out);
    permute_kernel<<<dim3(512 * 8), dim3(256), 0, stream>>>(pred, ws_inv, out);
}

// Round 2
// 125.714 us; speedup vs baseline: 1.2278x; 1.2278x over previous
//
#include <hip/hip_runtime.h>

// B=64, K=8, H=W=128 (HW=16384). float32 in/out.
// out[0] = loss scalar; out[1..] = pred_perm (B,K,H,W) flat.
//
// Pipeline:
//   cost_kernel   : per-(b,chunk) partial sums of cross[i][j] = sum_hw t_j*log(p_i+eps)
//                   and ent[j] = sum_hw t_j*log(t_j+eps); no atomics (disjoint slots).
//   assign_kernel : reduce partials -> C; Held-Karp DP over 8! assignments; inv perm + per-b loss.
//   permute_kernel: out[b,j] = pred[b, inv[b][j]]; block 0 wave 0 also sums ws_loss -> out[0].

#define BB 64
#define KK 8
#define HW 16384
#define CH 16        // chunks per batch for cost_kernel
#define CHUNK 1024   // hw positions per chunk
#define EPSF 1e-15f

// ---------- compile-time mask table: all 255 nonzero 8-bit masks, level-ordered by popcount ----------
struct MaskTab {
    unsigned char masks[255];
    int off[9];
};

constexpr MaskTab make_tab() {
    MaskTab t{};
    int idx = 0;
    for (int p = 1; p <= 8; ++p) {
        t.off[p - 1] = idx;
        for (int m = 1; m < 256; ++m) {
            int c = 0;
            for (int b = 0; b < 8; ++b) c += (m >> b) & 1;
            if (c == p) t.masks[idx++] = (unsigned char)m;
        }
    }
    t.off[8] = idx;
    return t;
}

__constant__ MaskTab kTab = make_tab();

__device__ __forceinline__ float dot4(float4 t, float4 l) {
    return t.x * l.x + t.y * l.y + t.z * l.z + t.w * l.w;
}

// ---------- phase 1: partial cross/ent sums ----------
// grid: B*CH blocks of 256 threads (4 waves). Wave w owns pred rows {2w, 2w+1}
// (16 accumulators) and ent rows {2w, 2w+1}. All 4 waves sweep the same
// 1024-position chunk; aug rows are read 4x but served from L1/L2.
__global__ __launch_bounds__(256) void cost_kernel(const float* __restrict__ pred,
                                                   const float* __restrict__ aug,
                                                   float* __restrict__ part)   // [B*CH][72]
{
    const int blk   = blockIdx.x;        // b*CH + chunk
    const int b     = blk >> 4;
    const int chunk = blk & 15;
    const int tid   = threadIdx.x;
    const int wave  = tid >> 6;
    const int lane  = tid & 63;

    const float* p0  = pred + (size_t)b * (KK * HW) + (size_t)(2 * wave) * HW + chunk * CHUNK;
    const float* p1  = p0 + HW;
    const float* tb  = aug + (size_t)b * (KK * HW) + chunk * CHUNK;
    const float* t0b = tb + (size_t)(2 * wave) * HW;
    const float* t1b = t0b + HW;

    float acc[16];
#pragma unroll
    for (int v = 0; v < 16; ++v) acc[v] = 0.f;
    float e0 = 0.f, e1 = 0.f;

#pragma unroll
    for (int it = 0; it < 4; ++it) {
        const int off = it * 256 + lane * 4;

        float4 a4 = *(const float4*)(p0 + off);
        float4 c4 = *(const float4*)(p1 + off);
        float4 la, lc;
        la.x = __logf(a4.x + EPSF); la.y = __logf(a4.y + EPSF);
        la.z = __logf(a4.z + EPSF); la.w = __logf(a4.w + EPSF);
        lc.x = __logf(c4.x + EPSF); lc.y = __logf(c4.y + EPSF);
        lc.z = __logf(c4.z + EPSF); lc.w = __logf(c4.w + EPSF);

#pragma unroll
        for (int j = 0; j < 8; ++j) {
            float4 t4 = *(const float4*)(tb + (size_t)j * HW + off);
            acc[j]     += dot4(t4, la);
            acc[8 + j] += dot4(t4, lc);
        }

        float4 t0 = *(const float4*)(t0b + off);
        float4 t1 = *(const float4*)(t1b + off);
        e0 += t0.x * __logf(t0.x + EPSF) + t0.y * __logf(t0.y + EPSF)
            + t0.z * __logf(t0.z + EPSF) + t0.w * __logf(t0.w + EPSF);
        e1 += t1.x * __logf(t1.x + EPSF) + t1.y * __logf(t1.y + EPSF)
            + t1.z * __logf(t1.z + EPSF) + t1.w * __logf(t1.w + EPSF);
    }

    // wave-wide butterfly reduce: 18 values
#pragma unroll
    for (int v = 0; v < 16; ++v) {
        float s = acc[v];
#pragma unroll
        for (int d = 1; d < 64; d <<= 1) s += __shfl_xor(s, d);
        acc[v] = s;
    }
#pragma unroll
    for (int d = 1; d < 64; d <<= 1) e0 += __shfl_xor(e0, d);
#pragma unroll
    for (int d = 1; d < 64; d <<= 1) e1 += __shfl_xor(e1, d);

    if (lane == 0) {
        float* dst = part + (size_t)blk * 72;
#pragma unroll
        for (int j = 0; j < 8; ++j) {
            dst[16 * wave + j]     = acc[j];       // cross[i=2w][j]
            dst[16 * wave + 8 + j] = acc[8 + j];   // cross[i=2w+1][j]
        }
        dst[64 + 2 * wave]     = e0;               // ent[2w]
        dst[64 + 2 * wave + 1] = e1;               // ent[2w+1]
    }
}

// ---------- phase 2: reduce partials + Held-Karp DP per batch ----------
// grid: B blocks of 64 threads (1 wave).
__global__ __launch_bounds__(64) void assign_kernel(const float* __restrict__ part,
                                                    int* __restrict__ ws_inv,     // [B][8]: col -> src row
                                                    float* __restrict__ ws_loss)  // [B]
{
    __shared__ float C[64];     // C[i*8+j] = ent[j] - cross[i][j] (unscaled)
    __shared__ float dp[256];
    __shared__ int   choice[256];

    const int b    = blockIdx.x;
    const int lane = threadIdx.x;
    const float* pb = part + (size_t)b * CH * 72;

    float s = 0.f;
#pragma unroll
    for (int c = 0; c < CH; ++c) s += pb[c * 72 + lane];
    float e = 0.f;
    if (lane < 8) {
#pragma unroll
        for (int c = 0; c < CH; ++c) e += pb[c * 72 + 64 + lane];
    }
    const float entj = __shfl(e, lane & 7);   // ent[j] lives in lane j (j<8)
    C[lane] = entj - s;
    if (lane == 0) dp[0] = 0.f;
    __syncthreads();

    const int grp = lane >> 3;
    const int j   = lane & 7;

    for (int p = 1; p <= 8; ++p) {
        const int start = kTab.off[p - 1];
        const int end   = kTab.off[p];
        const float* Crow = &C[(p - 1) * 8];
        for (int base = start; base < end; base += 8) {
            const int mi = base + grp;
            if (mi < end) {
                const int M = kTab.masks[mi];
                float v  = 1e30f;
                int   bj = 0;
                if (M & (1 << j)) {
                    v  = dp[M ^ (1 << j)] + Crow[j];
                    bj = j;
                }
#pragma unroll
                for (int d = 1; d < 8; d <<= 1) {
                    float ov = __shfl_xor(v, d);
                    int   oj = __shfl_xor(bj, d);
                    if (ov < v) { v = ov; bj = oj; }
                }
                if (j == 0) { dp[M] = v; choice[M] = bj; }
            }
        }
        __syncthreads();
    }

    if (lane == 0) {
        int mask = 255;
        for (int r = 7; r >= 0; --r) {
            const int jj = choice[mask];
            ws_inv[b * 8 + jj] = r;        // column jj takes pred row r
            mask ^= 1 << jj;
        }
        ws_loss[b] = dp[255] * (1.0f / (16384.0f * 512.0f));
    }
}

// ---------- phase 3: permuted copy + loss finalize ----------
// out[1 + (b*8+j)*HW + e] = pred[(b*8+inv[b][j])*HW + e].
// d_out+1 is only 4B-aligned -> scalar dword copies, lane-contiguous (coalesced).
__global__ __launch_bounds__(256) void permute_kernel(const float* __restrict__ pred,
                                                      const int* __restrict__ ws_inv,
                                                      const float* __restrict__ ws_loss,
                                                      float* __restrict__ out)
{
    const int blk    = blockIdx.x;
    const int pair   = blk >> 3;      // b*8 + j
    const int cchunk = blk & 7;
    const int b      = pair >> 3;

    const int src_row = ws_inv[pair]; // uniform per block

    const float* src = pred + ((size_t)b * 8 + src_row) * HW + cchunk * 2048;
    float*       dst = out + 1 + (size_t)pair * HW + cchunk * 2048;

    const int t = threadIdx.x;
#pragma unroll
    for (int m = 0; m < 8; ++m) dst[t + m * 256] = src[t + m * 256];

    if (blk == 0 && t < 64) {
        float v = ws_loss[t];
#pragma unroll
        for (int d = 1; d < 64; d <<= 1) v += __shfl_xor(v, d);
        if (t == 0) out[0] = v;
    }
}

extern "C" void kernel_launch(void* const* d_in, const int* in_sizes, int n_in,
                              void* d_out, int out_size, void* d_ws, size_t ws_size,
                              hipStream_t stream) {
    const float* pred = (const float*)d_in[0];
    const float* aug  = (const float*)d_in[1];
    float* out = (float*)d_out;

    float* part    = (float*)d_ws;                       // 64*16*72 floats
    int*   ws_inv  = (int*)(part + BB * CH * 72);        // 512 ints
    float* ws_loss = (float*)(ws_inv + BB * KK);         // 64 floats

    cost_kernel<<<dim3(BB * CH), dim3(256), 0, stream>>>(pred, aug, part);
    assign_kernel<<<dim3(BB), dim3(64), 0, stream>>>(part, ws_inv, ws_loss);
    permute_kernel<<<dim3(512 * 8), dim3(256), 0, stream>>>(pred, ws_inv, ws_loss, out);
}

// Round 3
// 123.272 us; speedup vs baseline: 1.2521x; 1.0198x over previous
//
#include <hip/hip_runtime.h>

// B=64, K=8, H=W=128 (HW=16384). float32 in/out.
// out[0] = loss scalar; out[1..] = pred_perm (B,K,H,W) flat.
//
// Pipeline (2 kernels + one 4-byte memset):
//   cost_kernel    : per-(b,chunk) partial sums of cross[i][j] = sum_hw t_j*log(p_i+eps)
//                    and ent[j] = sum_hw t_j*log(t_j+eps); disjoint slots, no atomics.
//   permute_kernel : every block redundantly reduces its batch's partials + runs the
//                    Held-Karp DP (cheap, parallel), then copies its half-row with
//                    float4 stores; one block per batch atomicAdds the loss into out[0].

#define BB 64
#define KK 8
#define HW 16384
#define CH 16        // chunks per batch for cost_kernel
#define CHUNK 1024   // hw positions per chunk
#define EPSF 1e-15f

// ---------- compile-time mask table: all 255 nonzero 8-bit masks, level-ordered by popcount ----------
struct MaskTab {
    unsigned char masks[255];
    int off[9];
};

constexpr MaskTab make_tab() {
    MaskTab t{};
    int idx = 0;
    for (int p = 1; p <= 8; ++p) {
        t.off[p - 1] = idx;
        for (int m = 1; m < 256; ++m) {
            int c = 0;
            for (int b = 0; b < 8; ++b) c += (m >> b) & 1;
            if (c == p) t.masks[idx++] = (unsigned char)m;
        }
    }
    t.off[8] = idx;
    return t;
}

__constant__ MaskTab kTab = make_tab();

__device__ __forceinline__ float dot4(float4 t, float4 l) {
    return t.x * l.x + t.y * l.y + t.z * l.z + t.w * l.w;
}

__device__ __forceinline__ float4 log4(float4 a) {
    float4 r;
    r.x = __logf(a.x + EPSF); r.y = __logf(a.y + EPSF);
    r.z = __logf(a.z + EPSF); r.w = __logf(a.w + EPSF);
    return r;
}

// ---------- phase 1: partial cross/ent sums ----------
// grid: B*CH blocks of 256 threads (4 waves). Wave w owns pred rows {2w, 2w+1}
// (16 accumulators); ent terms for aug rows {2w, 2w+1} are computed from the
// j-loop's own t4 loads (wave-uniform branch), saving 2 loads/iter.
__global__ __launch_bounds__(256) void cost_kernel(const float* __restrict__ pred,
                                                   const float* __restrict__ aug,
                                                   float* __restrict__ part)   // [B*CH][72]
{
    const int blk   = blockIdx.x;        // b*CH + chunk
    const int b     = blk >> 4;
    const int chunk = blk & 15;
    const int tid   = threadIdx.x;
    const int wave  = tid >> 6;
    const int lane  = tid & 63;
    const int w2    = 2 * wave;

    const float* p0 = pred + (size_t)b * (KK * HW) + (size_t)w2 * HW + chunk * CHUNK;
    const float* p1 = p0 + HW;
    const float* tb = aug + (size_t)b * (KK * HW) + chunk * CHUNK;

    float acc[16];
#pragma unroll
    for (int v = 0; v < 16; ++v) acc[v] = 0.f;
    float e0 = 0.f, e1 = 0.f;

#pragma unroll
    for (int it = 0; it < 4; ++it) {
        const int off = it * 256 + lane * 4;

        float4 la = log4(*(const float4*)(p0 + off));
        float4 lc = log4(*(const float4*)(p1 + off));

#pragma unroll
        for (int j = 0; j < 8; ++j) {
            float4 t4 = *(const float4*)(tb + (size_t)j * HW + off);
            acc[j]     += dot4(t4, la);
            acc[8 + j] += dot4(t4, lc);
            if (j == w2) {                    // wave-uniform, no lane divergence
                e0 += dot4(t4, log4(t4));
            } else if (j == w2 + 1) {
                e1 += dot4(t4, log4(t4));
            }
        }
    }

    // wave-wide butterfly reduce: 18 values
#pragma unroll
    for (int v = 0; v < 16; ++v) {
        float s = acc[v];
#pragma unroll
        for (int d = 1; d < 64; d <<= 1) s += __shfl_xor(s, d);
        acc[v] = s;
    }
#pragma unroll
    for (int d = 1; d < 64; d <<= 1) e0 += __shfl_xor(e0, d);
#pragma unroll
    for (int d = 1; d < 64; d <<= 1) e1 += __shfl_xor(e1, d);

    if (lane == 0) {
        float* dst = part + (size_t)blk * 72;
#pragma unroll
        for (int j = 0; j < 8; ++j) {
            dst[16 * wave + j]     = acc[j];       // cross[i=2w][j]
            dst[16 * wave + 8 + j] = acc[8 + j];   // cross[i=2w+1][j]
        }
        dst[64 + w2]     = e0;                     // ent[2w]
        dst[64 + w2 + 1] = e1;                     // ent[2w+1]
    }
}

// ---------- phase 2: fused DP + permuted copy ----------
// grid: 1024 blocks of 256 threads; block g handles half of pair p=g>>1 (half=g&1).
// Every block redundantly reduces partials for b=p>>3 and runs the Held-Karp DP
// (wall-time free: parallel, ~µs). Block g==16b also adds the batch loss to out[0].
// Stores: out+1 row base is 4B-aligned; element 3 of each row is 16B-aligned, so
// middle 4095 quads go out as float4; head 3 + tail 1 elements scalar (one thread).
__global__ __launch_bounds__(256) void permute_kernel(const float* __restrict__ pred,
                                                      const float* __restrict__ part,
                                                      float* __restrict__ out)
{
    __shared__ float red[72];
    __shared__ float C[64];     // C[i*8+j] = ent[j] - cross[i][j] (unscaled)
    __shared__ float dp[256];
    __shared__ int   choice[256];
    __shared__ int   inv8[8];   // col -> src row

    const int g    = blockIdx.x;
    const int p    = g >> 1;       // pair = b*8 + jcol
    const int half = g & 1;
    const int b    = p >> 3;
    const int tid  = threadIdx.x;

    // --- reduce partials for batch b ---
    const float* pb = part + (size_t)b * CH * 72;
    if (tid < 72) {
        float s = 0.f;
#pragma unroll
        for (int c = 0; c < CH; ++c) s += pb[c * 72 + tid];
        red[tid] = s;
    }
    __syncthreads();
    if (tid < 64) C[tid] = red[64 + (tid & 7)] - red[tid];
    if (tid == 0) dp[0] = 0.f;
    __syncthreads();

    // --- Held-Karp DP over 255 masks, level-ordered by popcount ---
    const int grp = tid >> 3;      // 32 mask slots per pass
    const int j   = tid & 7;

    for (int lvl = 1; lvl <= 8; ++lvl) {
        const int start = kTab.off[lvl - 1];
        const int end   = kTab.off[lvl];
        const float* Crow = &C[(lvl - 1) * 8];
        for (int base = start; base < end; base += 32) {
            const int mi = base + grp;
            if (mi < end) {
                const int M = kTab.masks[mi];
                float v  = 1e30f;
                int   bj = 0;
                if (M & (1 << j)) {
                    v  = dp[M ^ (1 << j)] + Crow[j];
                    bj = j;
                }
#pragma unroll
                for (int d = 1; d < 8; d <<= 1) {
                    float ov = __shfl_xor(v, d);
                    int   oj = __shfl_xor(bj, d);
                    if (ov < v) { v = ov; bj = oj; }
                }
                if (j == 0) { dp[M] = v; choice[M] = bj; }
            }
        }
        __syncthreads();
    }

    if (tid == 0) {
        int mask = 255;
        for (int r = 7; r >= 0; --r) {
            const int jj = choice[mask];
            inv8[jj] = r;              // column jj takes pred row r
            mask ^= 1 << jj;
        }
        if (g == (b << 4))             // exactly one block per batch
            atomicAdd(out, dp[255] * (1.0f / (16384.0f * 512.0f)));
    }
    __syncthreads();

    // --- permuted copy of half a row (8192 elements = 2048 quads) ---
    const int src_row = inv8[p & 7];   // uniform per block
    const float* src = pred + ((size_t)(b << 3) + src_row) * HW;
    float*       drow = out + 1 + (size_t)p * HW;

#pragma unroll
    for (int m = 0; m < 8; ++m) {
        const int f = half * 2048 + tid + 256 * m;   // quad index in [0,4096)
        const int e = 3 + 4 * f;
        if (f < 4095) {
            float4 v;
            v.x = src[e]; v.y = src[e + 1]; v.z = src[e + 2]; v.w = src[e + 3];
            *(float4*)(drow + e) = v;                // 16B-aligned: 1+3+4f ≡ 0 mod 4
        } else {                                     // f==4095: head 3 + tail 1
            drow[0] = src[0]; drow[1] = src[1]; drow[2] = src[2];
            drow[16383] = src[16383];
        }
    }
}

extern "C" void kernel_launch(void* const* d_in, const int* in_sizes, int n_in,
                              void* d_out, int out_size, void* d_ws, size_t ws_size,
                              hipStream_t stream) {
    const float* pred = (const float*)d_in[0];
    const float* aug  = (const float*)d_in[1];
    float* out = (float*)d_out;
    float* part = (float*)d_ws;                      // 64*16*72 floats

    hipMemsetAsync(d_out, 0, sizeof(float), stream); // zero the loss accumulator

    cost_kernel<<<dim3(BB * CH), dim3(256), 0, stream>>>(pred, aug, part);
    permute_kernel<<<dim3(1024), dim3(256), 0, stream>>>(pred, part, out);
}